// Round 17
// baseline (637.780 us; speedup 1.0000x reference)
//
#include <hip/hip_runtime.h>

// ---------------------------------------------------------------------------
// SpikingMLP forward. bf16 MFMA GEMMs, split-precision weights (W_hi+W_lo,
// RNE split). R17: W bypasses LDS entirely — global->reg (8 dwordx4/wave,
// depth-1 prefetch) -> in-reg RNE split -> MFMA B-operand. A stays on the
// proven global_load_lds dbuf path (32 KB LDS). One barrier per K-step.
// Per-acc K-order unchanged (kk asc, hi, lo) -> bit-identical spike trains.
// ---------------------------------------------------------------------------

#define T_STEPS 8
#define BATCH 64
#define F0 32768
#define DIM 2048
#define NROWS 512
#define NC 1000

typedef __attribute__((ext_vector_type(8))) short short8;   // 8 bf16
typedef __attribute__((ext_vector_type(4))) float f32x4;    // MFMA acc

__device__ __forceinline__ unsigned short bf16_rne(float f) {
    unsigned int u = __float_as_uint(f);
    u += 0x7FFFu + ((u >> 16) & 1u);
    return (unsigned short)(u >> 16);
}

#define BM 128
#define BN 128
#define BK 64

#define SBAR() do { __builtin_amdgcn_sched_barrier(0); \
                    __builtin_amdgcn_s_barrier();      \
                    __builtin_amdgcn_sched_barrier(0); } while (0)

__global__ __launch_bounds__(512) void gemm_splitk(
    const unsigned short* __restrict__ A, const float* __restrict__ W,
    float* __restrict__ part, int M, int N, int K, int Kpart, int Wrows)
{
    __shared__ unsigned short As[2][BM * BK];   // 2 x 16 KB (A dbuf only)

    // ---- XCD-chunked bijective remap (grid %8==0 at all call sites) ----
    const int gx = gridDim.x, gy = gridDim.y;
    const int nwg = gx * gy * gridDim.z;
    const int lid = blockIdx.x + gx * (blockIdx.y + gy * blockIdx.z);
    const int cpx = nwg >> 3;
    const int nid = (lid & 7) * cpx + (lid >> 3);
    const int bx  = nid % gx;
    const int by  = (nid / gx) % gy;
    const int kz  = nid / (gx * gy);

    const int tid  = threadIdx.x;
    const int lane = tid & 63;
    const int w    = tid >> 6;          // 0..7
    const int l15  = lane & 15;
    const int lh   = lane >> 4;         // 0..3
    const int bm   = bx * BM;
    const int bn   = by * BN;
    const int ks   = Kpart / BK;
    const int wm   = (w >> 2) * 64;     // 2 M-halves
    const int wn   = (w & 3) * 32;      // 4 N-quarters
    const int kbase = kz * Kpart;

    // per-lane W fragment row bases (row fixed per ni for whole kernel)
    size_t wrow[2];
#pragma unroll
    for (int ni = 0; ni < 2; ++ni) {
        const int r = min(bn + wn + ni * 16 + l15, Wrows - 1);
        wrow[ni] = (size_t)r * K;
    }

    f32x4 acc[4][2] = {};
    float4 wr[2][2][2];                 // [ni][kk][half] raw W prefetch
    short8 bh[2][2], bl[2][2];          // converted B fragments [ni][kk]

    auto issueW = [&](int kt) {
        const int k0 = kbase + kt * BK + lh * 8;
#pragma unroll
        for (int ni = 0; ni < 2; ++ni)
#pragma unroll
            for (int kk = 0; kk < 2; ++kk) {
                const float* p = W + wrow[ni] + k0 + kk * 32;
                wr[ni][kk][0] = *(const float4*)p;
                wr[ni][kk][1] = *(const float4*)(p + 4);
            }
    };
    auto issueA = [&](int buf, int kt) {
        const int k0 = kbase + kt * BK;
#pragma unroll
        for (int c = 0; c < 2; ++c) {
            const int r    = w * 16 + c * 8 + (lane >> 3);
            const int colb = ((lane & 7) * 16) ^ ((r & 7) << 4);
            const char* src = (const char*)A + ((size_t)(bm + r) * K + k0) * 2 + colb;
            unsigned short* dst = &As[buf][(w * 16 + c * 8) * BK];
            __builtin_amdgcn_global_load_lds(
                (const __attribute__((address_space(1))) void*)src,
                (__attribute__((address_space(3))) void*)dst, 16, 0, 0);
        }
    };
    auto convertW = [&]() {
#pragma unroll
        for (int ni = 0; ni < 2; ++ni)
#pragma unroll
            for (int kk = 0; kk < 2; ++kk) {
                const float vf[8] = {wr[ni][kk][0].x, wr[ni][kk][0].y,
                                     wr[ni][kk][0].z, wr[ni][kk][0].w,
                                     wr[ni][kk][1].x, wr[ni][kk][1].y,
                                     wr[ni][kk][1].z, wr[ni][kk][1].w};
                unsigned hw[4], lw[4];
#pragma unroll
                for (int p = 0; p < 4; ++p) {
                    const unsigned ua = __float_as_uint(vf[2 * p]);
                    const unsigned ub = __float_as_uint(vf[2 * p + 1]);
                    const unsigned ra = (ua + 0x7FFFu + ((ua >> 16) & 1u)) & 0xFFFF0000u;
                    const unsigned rb = (ub + 0x7FFFu + ((ub >> 16) & 1u)) & 0xFFFF0000u;
                    hw[p] = (ra >> 16) | rb;
                    const float la = vf[2 * p]     - __uint_as_float(ra);
                    const float lb = vf[2 * p + 1] - __uint_as_float(rb);
                    unsigned lo;
                    asm("v_cvt_pk_bf16_f32 %0, %1, %2" : "=v"(lo) : "v"(la), "v"(lb));
                    lw[p] = lo;
                }
                uint4 hv = make_uint4(hw[0], hw[1], hw[2], hw[3]);
                uint4 lv = make_uint4(lw[0], lw[1], lw[2], lw[3]);
                bh[ni][kk] = *(short8*)&hv;
                bl[ni][kk] = *(short8*)&lv;
            }
    };
    auto mfmaStep = [&](int cb) {
#pragma unroll
        for (int kk = 0; kk < 2; ++kk) {
            const int kb = (kk * 32 + lh * 8) * 2;
#pragma unroll
            for (int mi = 0; mi < 4; ++mi) {
                const int r = wm + mi * 16 + l15;
                const short8 a = *(const short8*)(
                    (const char*)&As[cb][0] + r * 128 + (kb ^ ((r & 7) << 4)));
#pragma unroll
                for (int ni = 0; ni < 2; ++ni) {
                    acc[mi][ni] = __builtin_amdgcn_mfma_f32_16x16x32_bf16(
                        a, bh[ni][kk], acc[mi][ni], 0, 0, 0);
                    acc[mi][ni] = __builtin_amdgcn_mfma_f32_16x16x32_bf16(
                        a, bl[ni][kk], acc[mi][ni], 0, 0, 0);
                }
            }
        }
    };

    // ---- prologue: stage tile 0 ----
    issueW(0);
    issueA(0, 0);
    convertW();                                   // auto vmcnt(2): W retired
    asm volatile("s_waitcnt vmcnt(0) lgkmcnt(0)" ::: "memory");
    SBAR();

    int cb = 0;
    for (int t = 0; t < ks; ++t) {
        const bool last = (t + 1 == ks);
        if (!last) { issueW(t + 1); issueA(cb ^ 1, t + 1); }
        mfmaStep(cb);                             // pure LDS+reg -> MFMA
        if (!last) {
            convertW();                           // auto vmcnt(2): A-DMA stays out
            asm volatile("s_waitcnt vmcnt(0) lgkmcnt(0)" ::: "memory");
            SBAR();
            cb ^= 1;
        }
    }

    // ---- epilogue: partial store (C/D: col=lane&15, row=(lane>>4)*4+e) ----
    const size_t zoff = (size_t)kz * M * N;
#pragma unroll
    for (int mi = 0; mi < 4; ++mi) {
        const int gr0 = bm + wm + mi * 16 + lh * 4;
#pragma unroll
        for (int ni = 0; ni < 2; ++ni) {
            const int gc = bn + wn + ni * 16 + l15;
            if (gc < N) {
#pragma unroll
                for (int e = 0; e < 4; ++e) {
                    const int gr = gr0 + e;
                    if (gr < M) part[zoff + (size_t)gr * N + gc] = acc[mi][ni][e];
                }
            }
        }
    }
}

// part[KS][.][N] summed + bias -> out (fp32)
__global__ __launch_bounds__(256) void reduce_bias(
    const float* __restrict__ part, const float* __restrict__ bias,
    float* __restrict__ out, int KS, int MN, int N)
{
    const int i4 = blockIdx.x * 256 + threadIdx.x;
    if (i4 * 4 >= MN) return;
    float4 s = make_float4(0.f, 0.f, 0.f, 0.f);
    for (int z = 0; z < KS; ++z) {
        const float4 p = *(const float4*)&part[(size_t)z * MN + i4 * 4];
        s.x += p.x; s.y += p.y; s.z += p.z; s.w += p.w;
    }
    const int col = (i4 * 4) % N;
    const float4 b = *(const float4*)&bias[col];
    s.x += b.x; s.y += b.y; s.z += b.z; s.w += b.w;
    *(float4*)&out[(size_t)i4 * 4] = s;
}

// IF neuron on raw input, vectorized x4
__global__ __launch_bounds__(256) void if0_kernel(
    const float* __restrict__ x, unsigned short* __restrict__ s)
{
    const size_t id4 = ((size_t)blockIdx.x * 256 + threadIdx.x) * 4;
    float v0 = 0.f, v1 = 0.f, v2 = 0.f, v3 = 0.f;
#pragma unroll
    for (int t = 0; t < T_STEPS; ++t) {
        const size_t idx = (size_t)t * (BATCH * (size_t)F0) + id4;
        const float4 xv = *(const float4*)&x[idx];
        ushort4 o;
        v0 += xv.x; if (v0 >= 1.f) { o.x = 0x3F80; v0 = 0.f; } else o.x = 0;
        v1 += xv.y; if (v1 >= 1.f) { o.y = 0x3F80; v1 = 0.f; } else o.y = 0;
        v2 += xv.z; if (v2 >= 1.f) { o.z = 0x3F80; v2 = 0.f; } else o.z = 0;
        v3 += xv.w; if (v3 >= 1.f) { o.w = 0x3F80; v3 = 0.f; } else o.w = 0;
        *(ushort4*)&s[idx] = o;
    }
}

// Fused BN stats + BN apply + IF (stats order unchanged)
__global__ __launch_bounds__(256) void bn_stats_if(
    const float* __restrict__ z, const float* __restrict__ g,
    const float* __restrict__ be, unsigned short* __restrict__ s)
{
    __shared__ float ssum[4][64], ssq[4][64];
    __shared__ float ssc[64], ssh[64];
    const int l = threadIdx.x & 63;
    const int q = threadIdx.x >> 6;
    const int f = blockIdx.x * 64 + l;
    float sum = 0.f, sq = 0.f;
    for (int r = q; r < NROWS; r += 4) {
        const float v = z[(size_t)r * DIM + f];
        sum += v; sq += v * v;
    }
    ssum[q][l] = sum; ssq[q][l] = sq;
    __syncthreads();
    if (threadIdx.x < 64) {
        float ts = 0.f, tq = 0.f;
#pragma unroll
        for (int i = 0; i < 4; ++i) { ts += ssum[i][l]; tq += ssq[i][l]; }
        const float mean = ts * (1.0f / NROWS);
        const float var  = tq * (1.0f / NROWS) - mean * mean;
        const float inv  = rsqrtf(var + 1e-5f);
        const float sc   = g[f] * inv;
        ssc[l] = sc;
        ssh[l] = be[f] - mean * sc;
    }
    __syncthreads();
    const float sc = ssc[l];
    const float sh = ssh[l];
    for (int b = q; b < BATCH; b += 4) {
        const int id = b * DIM + f;
        float v = 0.f;
#pragma unroll
        for (int t = 0; t < T_STEPS; ++t) {
            const size_t idx = (size_t)t * (BATCH * DIM) + id;
            v += z[idx] * sc + sh;
            if (v >= 1.0f) { s[idx] = 0x3F80; v = 0.f; }
            else           { s[idx] = 0; }
        }
    }
}

// Layer-2 variant: emit only the T-mean of spikes (bf16, k/8 exact)
__global__ __launch_bounds__(256) void bn_stats_if_mean(
    const float* __restrict__ z, const float* __restrict__ g,
    const float* __restrict__ be, unsigned short* __restrict__ sbar)
{
    __shared__ float ssum[4][64], ssq[4][64];
    __shared__ float ssc[64], ssh[64];
    const int l = threadIdx.x & 63;
    const int q = threadIdx.x >> 6;
    const int f = blockIdx.x * 64 + l;
    float sum = 0.f, sq = 0.f;
    for (int r = q; r < NROWS; r += 4) {
        const float v = z[(size_t)r * DIM + f];
        sum += v; sq += v * v;
    }
    ssum[q][l] = sum; ssq[q][l] = sq;
    __syncthreads();
    if (threadIdx.x < 64) {
        float ts = 0.f, tq = 0.f;
#pragma unroll
        for (int i = 0; i < 4; ++i) { ts += ssum[i][l]; tq += ssq[i][l]; }
        const float mean = ts * (1.0f / NROWS);
        const float var  = tq * (1.0f / NROWS) - mean * mean;
        const float inv  = rsqrtf(var + 1e-5f);
        const float sc   = g[f] * inv;
        ssc[l] = sc;
        ssh[l] = be[f] - mean * sc;
    }
    __syncthreads();
    const float sc = ssc[l];
    const float sh = ssh[l];
    for (int b = q; b < BATCH; b += 4) {
        const int id = b * DIM + f;
        float v = 0.f;
        int cnt = 0;
#pragma unroll
        for (int t = 0; t < T_STEPS; ++t) {
            const size_t idx = (size_t)t * (BATCH * DIM) + id;
            v += z[idx] * sc + sh;
            if (v >= 1.0f) { cnt++; v = 0.f; }
        }
        sbar[id] = bf16_rne((float)cnt * 0.125f);
    }
}

extern "C" void kernel_launch(void* const* d_in, const int* in_sizes, int n_in,
                              void* d_out, int out_size, void* d_ws, size_t ws_size,
                              hipStream_t stream)
{
    const float* x    = (const float*)d_in[0];
    const float* W0   = (const float*)d_in[1];
    const float* b0   = (const float*)d_in[2];
    const float* g0   = (const float*)d_in[3];
    const float* be0  = (const float*)d_in[4];
    const float* W1   = (const float*)d_in[5];
    const float* b1   = (const float*)d_in[6];
    const float* g1   = (const float*)d_in[7];
    const float* be1  = (const float*)d_in[8];
    const float* W2   = (const float*)d_in[9];
    const float* b2   = (const float*)d_in[10];
    const float* g2   = (const float*)d_in[11];
    const float* be2  = (const float*)d_in[12];
    const float* Wout = (const float*)d_in[13];
    const float* bout = (const float*)d_in[14];
    float* out = (float*)d_out;
    (void)in_sizes; (void)n_in; (void)out_size; (void)ws_size;

    char* ws = (char*)d_ws;
    size_t off = 0;
    auto alloc = [&](size_t nbytes) {
        char* p = ws + off;
        off = (off + nbytes + 255) & ~(size_t)255;
        return p;
    };
    unsigned short* s0 = (unsigned short*)alloc((size_t)NROWS * F0 * 2);  // 33.5 MB
    unsigned short* s1 = (unsigned short*)alloc((size_t)NROWS * DIM * 2);
    unsigned short* s2 = (unsigned short*)alloc((size_t)NROWS * DIM * 2);
    unsigned short* sb = (unsigned short*)alloc((size_t)128 * DIM * 2);   // 128-row pad
    float* z    = (float*)alloc((size_t)NROWS * DIM * 4);
    float* part = (float*)alloc((size_t)16 * NROWS * DIM * 4);            // 67 MB

    const int MN = NROWS * DIM;

    // sn0 (vectorized x4)
    if0_kernel<<<(BATCH * (size_t)F0) / 4 / 256, 256, 0, stream>>>(x, s0);

    // layer 0: K=32768, KS=16  (grid 4*16*16=1024; ks=32)
    gemm_splitk<<<dim3(NROWS / BM, DIM / BN, 16), 512, 0, stream>>>(
        s0, W0, part, NROWS, DIM, F0, F0 / 16, DIM);
    reduce_bias<<<MN / 4 / 256, 256, 0, stream>>>(part, b0, z, 16, MN, DIM);
    bn_stats_if<<<DIM / 64, 256, 0, stream>>>(z, g0, be0, s1);

    // layer 1: K=2048, KS=8  (grid 512; ks=4)
    gemm_splitk<<<dim3(NROWS / BM, DIM / BN, 8), 512, 0, stream>>>(
        s1, W1, part, NROWS, DIM, DIM, DIM / 8, DIM);
    reduce_bias<<<MN / 4 / 256, 256, 0, stream>>>(part, b1, z, 8, MN, DIM);
    bn_stats_if<<<DIM / 64, 256, 0, stream>>>(z, g1, be1, s2);

    // layer 2: fused bn+if+T-mean
    gemm_splitk<<<dim3(NROWS / BM, DIM / BN, 8), 512, 0, stream>>>(
        s2, W2, part, NROWS, DIM, DIM, DIM / 8, DIM);
    reduce_bias<<<MN / 4 / 256, 256, 0, stream>>>(part, b2, z, 8, MN, DIM);
    bn_stats_if_mean<<<DIM / 64, 256, 0, stream>>>(z, g2, be2, sb);

    // readout: [64,2048] x [1000,2048]^T, KS=8 (grid 1*8*8=64; ks=4)
    gemm_splitk<<<dim3(1, (NC + BN - 1) / BN, 8), 512, 0, stream>>>(
        sb, Wout, part, BATCH, NC, DIM, DIM / 8, NC);
    reduce_bias<<<(BATCH * NC / 4 + 255) / 256, 256, 0, stream>>>(
        part, bout, out, 8, BATCH * NC, NC);
}

// Round 18
// 410.234 us; speedup vs baseline: 1.5547x; 1.5547x over previous
//
#include <hip/hip_runtime.h>

// ---------------------------------------------------------------------------
// SpikingMLP forward. bf16 MFMA GEMMs, split-precision weights (W_hi+W_lo,
// RNE split, converted during staging). R18 = consolidation at the measured
// optimum: R10's gemm structure (128^2 tile, BK=64, 8 waves, single-buf
// 2-phase, KS0=16 -> 3 blocks/CU cross-block overlap — best of 8 structural
// variants, 188 us) + R14's bit-identical cheap masked-RNE convert + setprio.
// Spike trains bit-identical to R10/R11/R14 (absmax 0.00390625).
// ---------------------------------------------------------------------------

#define T_STEPS 8
#define BATCH 64
#define F0 32768
#define DIM 2048
#define NROWS 512
#define NC 1000

typedef __attribute__((ext_vector_type(8))) short short8;   // 8 bf16
typedef __attribute__((ext_vector_type(4))) float f32x4;    // MFMA acc

__device__ __forceinline__ unsigned short bf16_rne(float f) {
    unsigned int u = __float_as_uint(f);
    u += 0x7FFFu + ((u >> 16) & 1u);
    return (unsigned short)(u >> 16);
}

#define BM 128
#define BN 128
#define BK 64

__device__ __forceinline__ short8 lds_frag(const unsigned short* base, int row, int kb) {
    const int off = row * 128 + (kb ^ ((row & 7) << 4));
    return *(const short8*)((const char*)base + off);
}

__global__ __launch_bounds__(512) void gemm_splitk(
    const unsigned short* __restrict__ A, const float* __restrict__ W,
    float* __restrict__ part, int M, int N, int K, int Kpart, int Wrows)
{
    __shared__ unsigned short As[BM * BK];   // 16 KB
    __shared__ unsigned short Hs[BN * BK];   // 16 KB (W hi)
    __shared__ unsigned short Ls[BN * BK];   // 16 KB (W lo)

    // ---- XCD-chunked bijective remap (grid %8==0 at all call sites) ----
    const int gx = gridDim.x, gy = gridDim.y;
    const int nwg = gx * gy * gridDim.z;
    const int lid = blockIdx.x + gx * (blockIdx.y + gy * blockIdx.z);
    const int cpx = nwg >> 3;
    const int nid = (lid & 7) * cpx + (lid >> 3);
    const int bx  = nid % gx;
    const int by  = (nid / gx) % gy;
    const int kz  = nid / (gx * gy);

    const int tid  = threadIdx.x;
    const int lane = tid & 63;
    const int w    = tid >> 6;          // 0..7
    const int bm   = bx * BM;
    const int bn   = by * BN;
    const int ksteps = Kpart / BK;
    const int wm = (w >> 2) * 64;       // 2 M-halves
    const int wn = (w & 3) * 32;        // 4 N-quarters

    f32x4 acc[4][2] = {};

    for (int kt = 0; kt < ksteps; ++kt) {
        const int k0 = kz * Kpart + kt * BK;

        // ---- A tile: global_load_lds, linear dst + XOR'd src ----
#pragma unroll
        for (int c = 0; c < 2; ++c) {
            const int r    = w * 16 + c * 8 + (lane >> 3);
            const int colb = ((lane & 7) * 16) ^ ((r & 7) << 4);
            const char* src = (const char*)A + ((size_t)(bm + r) * K + k0) * 2 + colb;
            unsigned short* dst = &As[(w * 16 + c * 8) * BK];
            __builtin_amdgcn_global_load_lds(
                (const __attribute__((address_space(1))) void*)src,
                (__attribute__((address_space(3))) void*)dst, 16, 0, 0);
        }

        // ---- W tile: fp32 loads -> cheap masked-RNE hi + cvt_pk lo ----
        float4 wv[4];
#pragma unroll
        for (int i = 0; i < 4; ++i) {
            const int q  = tid + 512 * i;
            const int n  = q >> 4;
            const int c4 = q & 15;
            const int gn = min(bn + n, Wrows - 1);
            wv[i] = *(const float4*)&W[(size_t)gn * K + k0 + c4 * 4];
        }
#pragma unroll
        for (int i = 0; i < 4; ++i) {
            const int q  = tid + 512 * i;
            const int n  = q >> 4;
            const int c4 = q & 15;
            const unsigned u0 = __float_as_uint(wv[i].x);
            const unsigned u1 = __float_as_uint(wv[i].y);
            const unsigned u2 = __float_as_uint(wv[i].z);
            const unsigned u3 = __float_as_uint(wv[i].w);
            // RNE-rounded hi bit-pattern (== bf16_rne<<16)
            const unsigned r0 = (u0 + 0x7FFFu + ((u0 >> 16) & 1u)) & 0xFFFF0000u;
            const unsigned r1 = (u1 + 0x7FFFu + ((u1 >> 16) & 1u)) & 0xFFFF0000u;
            const unsigned r2 = (u2 + 0x7FFFu + ((u2 >> 16) & 1u)) & 0xFFFF0000u;
            const unsigned r3 = (u3 + 0x7FFFu + ((u3 >> 16) & 1u)) & 0xFFFF0000u;
            const unsigned hi01 = (r0 >> 16) | r1;
            const unsigned hi23 = (r2 >> 16) | r3;
            const float l0 = wv[i].x - __uint_as_float(r0);
            const float l1 = wv[i].y - __uint_as_float(r1);
            const float l2 = wv[i].z - __uint_as_float(r2);
            const float l3 = wv[i].w - __uint_as_float(r3);
            unsigned lo01, lo23;
            asm("v_cvt_pk_bf16_f32 %0, %1, %2" : "=v"(lo01) : "v"(l0), "v"(l1));
            asm("v_cvt_pk_bf16_f32 %0, %1, %2" : "=v"(lo23) : "v"(l2), "v"(l3));
            const int off = n * 128 + ((c4 * 8) ^ ((n & 7) << 4));
            *(uint2*)((char*)Hs + off) = make_uint2(hi01, hi23);
            *(uint2*)((char*)Ls + off) = make_uint2(lo01, lo23);
        }

        __syncthreads();   // drains vmcnt (A dma) + lgkmcnt (W ds_writes)

        // ---- MFMA: acc += A*Whi + A*Wlo (pure LDS->MFMA, prioritized) ----
        __builtin_amdgcn_s_setprio(1);
#pragma unroll
        for (int kk = 0; kk < 2; ++kk) {
            const int kb = (kk * 32 + (lane >> 4) * 8) * 2;
            short8 a[4], bh[2], bl[2];
#pragma unroll
            for (int i = 0; i < 4; ++i)
                a[i] = lds_frag(As, wm + i * 16 + (lane & 15), kb);
#pragma unroll
            for (int i = 0; i < 2; ++i) {
                const int r = wn + i * 16 + (lane & 15);
                bh[i] = lds_frag(Hs, r, kb);
                bl[i] = lds_frag(Ls, r, kb);
            }
#pragma unroll
            for (int mi = 0; mi < 4; ++mi)
#pragma unroll
                for (int ni = 0; ni < 2; ++ni) {
                    acc[mi][ni] = __builtin_amdgcn_mfma_f32_16x16x32_bf16(
                        a[mi], bh[ni], acc[mi][ni], 0, 0, 0);
                    acc[mi][ni] = __builtin_amdgcn_mfma_f32_16x16x32_bf16(
                        a[mi], bl[ni], acc[mi][ni], 0, 0, 0);
                }
        }
        __builtin_amdgcn_s_setprio(0);
        __syncthreads();
    }

    // ---- epilogue: partial store (C/D: col=lane&15, row=(lane>>4)*4+e) ----
    const size_t zoff = (size_t)kz * M * N;
#pragma unroll
    for (int mi = 0; mi < 4; ++mi) {
        const int gr0 = bm + wm + mi * 16 + (lane >> 4) * 4;
#pragma unroll
        for (int ni = 0; ni < 2; ++ni) {
            const int gc = bn + wn + ni * 16 + (lane & 15);
            if (gc < N) {
#pragma unroll
                for (int e = 0; e < 4; ++e) {
                    const int gr = gr0 + e;
                    if (gr < M) part[zoff + (size_t)gr * N + gc] = acc[mi][ni][e];
                }
            }
        }
    }
}

// part[KS][.][N] summed + bias -> out (fp32)
__global__ __launch_bounds__(256) void reduce_bias(
    const float* __restrict__ part, const float* __restrict__ bias,
    float* __restrict__ out, int KS, int MN, int N)
{
    const int i4 = blockIdx.x * 256 + threadIdx.x;
    if (i4 * 4 >= MN) return;
    float4 s = make_float4(0.f, 0.f, 0.f, 0.f);
    for (int z = 0; z < KS; ++z) {
        const float4 p = *(const float4*)&part[(size_t)z * MN + i4 * 4];
        s.x += p.x; s.y += p.y; s.z += p.z; s.w += p.w;
    }
    const int col = (i4 * 4) % N;
    const float4 b = *(const float4*)&bias[col];
    s.x += b.x; s.y += b.y; s.z += b.z; s.w += b.w;
    *(float4*)&out[(size_t)i4 * 4] = s;
}

// IF neuron on raw input, vectorized x4
__global__ __launch_bounds__(256) void if0_kernel(
    const float* __restrict__ x, unsigned short* __restrict__ s)
{
    const size_t id4 = ((size_t)blockIdx.x * 256 + threadIdx.x) * 4;
    float v0 = 0.f, v1 = 0.f, v2 = 0.f, v3 = 0.f;
#pragma unroll
    for (int t = 0; t < T_STEPS; ++t) {
        const size_t idx = (size_t)t * (BATCH * (size_t)F0) + id4;
        const float4 xv = *(const float4*)&x[idx];
        ushort4 o;
        v0 += xv.x; if (v0 >= 1.f) { o.x = 0x3F80; v0 = 0.f; } else o.x = 0;
        v1 += xv.y; if (v1 >= 1.f) { o.y = 0x3F80; v1 = 0.f; } else o.y = 0;
        v2 += xv.z; if (v2 >= 1.f) { o.z = 0x3F80; v2 = 0.f; } else o.z = 0;
        v3 += xv.w; if (v3 >= 1.f) { o.w = 0x3F80; v3 = 0.f; } else o.w = 0;
        *(ushort4*)&s[idx] = o;
    }
}

// Fused BN stats + BN apply + IF (stats order unchanged)
__global__ __launch_bounds__(256) void bn_stats_if(
    const float* __restrict__ z, const float* __restrict__ g,
    const float* __restrict__ be, unsigned short* __restrict__ s)
{
    __shared__ float ssum[4][64], ssq[4][64];
    __shared__ float ssc[64], ssh[64];
    const int l = threadIdx.x & 63;
    const int q = threadIdx.x >> 6;
    const int f = blockIdx.x * 64 + l;
    float sum = 0.f, sq = 0.f;
    for (int r = q; r < NROWS; r += 4) {
        const float v = z[(size_t)r * DIM + f];
        sum += v; sq += v * v;
    }
    ssum[q][l] = sum; ssq[q][l] = sq;
    __syncthreads();
    if (threadIdx.x < 64) {
        float ts = 0.f, tq = 0.f;
#pragma unroll
        for (int i = 0; i < 4; ++i) { ts += ssum[i][l]; tq += ssq[i][l]; }
        const float mean = ts * (1.0f / NROWS);
        const float var  = tq * (1.0f / NROWS) - mean * mean;
        const float inv  = rsqrtf(var + 1e-5f);
        const float sc   = g[f] * inv;
        ssc[l] = sc;
        ssh[l] = be[f] - mean * sc;
    }
    __syncthreads();
    const float sc = ssc[l];
    const float sh = ssh[l];
    for (int b = q; b < BATCH; b += 4) {
        const int id = b * DIM + f;
        float v = 0.f;
#pragma unroll
        for (int t = 0; t < T_STEPS; ++t) {
            const size_t idx = (size_t)t * (BATCH * DIM) + id;
            v += z[idx] * sc + sh;
            if (v >= 1.0f) { s[idx] = 0x3F80; v = 0.f; }
            else           { s[idx] = 0; }
        }
    }
}

// Layer-2 variant: emit only the T-mean of spikes (bf16, k/8 exact)
__global__ __launch_bounds__(256) void bn_stats_if_mean(
    const float* __restrict__ z, const float* __restrict__ g,
    const float* __restrict__ be, unsigned short* __restrict__ sbar)
{
    __shared__ float ssum[4][64], ssq[4][64];
    __shared__ float ssc[64], ssh[64];
    const int l = threadIdx.x & 63;
    const int q = threadIdx.x >> 6;
    const int f = blockIdx.x * 64 + l;
    float sum = 0.f, sq = 0.f;
    for (int r = q; r < NROWS; r += 4) {
        const float v = z[(size_t)r * DIM + f];
        sum += v; sq += v * v;
    }
    ssum[q][l] = sum; ssq[q][l] = sq;
    __syncthreads();
    if (threadIdx.x < 64) {
        float ts = 0.f, tq = 0.f;
#pragma unroll
        for (int i = 0; i < 4; ++i) { ts += ssum[i][l]; tq += ssq[i][l]; }
        const float mean = ts * (1.0f / NROWS);
        const float var  = tq * (1.0f / NROWS) - mean * mean;
        const float inv  = rsqrtf(var + 1e-5f);
        const float sc   = g[f] * inv;
        ssc[l] = sc;
        ssh[l] = be[f] - mean * sc;
    }
    __syncthreads();
    const float sc = ssc[l];
    const float sh = ssh[l];
    for (int b = q; b < BATCH; b += 4) {
        const int id = b * DIM + f;
        float v = 0.f;
        int cnt = 0;
#pragma unroll
        for (int t = 0; t < T_STEPS; ++t) {
            const size_t idx = (size_t)t * (BATCH * DIM) + id;
            v += z[idx] * sc + sh;
            if (v >= 1.0f) { cnt++; v = 0.f; }
        }
        sbar[id] = bf16_rne((float)cnt * 0.125f);
    }
}

extern "C" void kernel_launch(void* const* d_in, const int* in_sizes, int n_in,
                              void* d_out, int out_size, void* d_ws, size_t ws_size,
                              hipStream_t stream)
{
    const float* x    = (const float*)d_in[0];
    const float* W0   = (const float*)d_in[1];
    const float* b0   = (const float*)d_in[2];
    const float* g0   = (const float*)d_in[3];
    const float* be0  = (const float*)d_in[4];
    const float* W1   = (const float*)d_in[5];
    const float* b1   = (const float*)d_in[6];
    const float* g1   = (const float*)d_in[7];
    const float* be1  = (const float*)d_in[8];
    const float* W2   = (const float*)d_in[9];
    const float* b2   = (const float*)d_in[10];
    const float* g2   = (const float*)d_in[11];
    const float* be2  = (const float*)d_in[12];
    const float* Wout = (const float*)d_in[13];
    const float* bout = (const float*)d_in[14];
    float* out = (float*)d_out;
    (void)in_sizes; (void)n_in; (void)out_size; (void)ws_size;

    char* ws = (char*)d_ws;
    size_t off = 0;
    auto alloc = [&](size_t nbytes) {
        char* p = ws + off;
        off = (off + nbytes + 255) & ~(size_t)255;
        return p;
    };
    unsigned short* s0 = (unsigned short*)alloc((size_t)NROWS * F0 * 2);  // 33.5 MB
    unsigned short* s1 = (unsigned short*)alloc((size_t)NROWS * DIM * 2);
    unsigned short* s2 = (unsigned short*)alloc((size_t)NROWS * DIM * 2);
    unsigned short* sb = (unsigned short*)alloc((size_t)128 * DIM * 2);   // 128-row pad
    float* z    = (float*)alloc((size_t)NROWS * DIM * 4);
    float* part = (float*)alloc((size_t)16 * NROWS * DIM * 4);            // 67 MB

    const int MN = NROWS * DIM;

    // sn0 (vectorized x4)
    if0_kernel<<<(BATCH * (size_t)F0) / 4 / 256, 256, 0, stream>>>(x, s0);

    // layer 0: K=32768, KS=16  (grid 4*16*16=1024, 3 blocks/CU)
    gemm_splitk<<<dim3(NROWS / BM, DIM / BN, 16), 512, 0, stream>>>(
        s0, W0, part, NROWS, DIM, F0, F0 / 16, DIM);
    reduce_bias<<<MN / 4 / 256, 256, 0, stream>>>(part, b0, z, 16, MN, DIM);
    bn_stats_if<<<DIM / 64, 256, 0, stream>>>(z, g0, be0, s1);

    // layer 1: K=2048, KS=8  (grid 512)
    gemm_splitk<<<dim3(NROWS / BM, DIM / BN, 8), 512, 0, stream>>>(
        s1, W1, part, NROWS, DIM, DIM, DIM / 8, DIM);
    reduce_bias<<<MN / 4 / 256, 256, 0, stream>>>(part, b1, z, 8, MN, DIM);
    bn_stats_if<<<DIM / 64, 256, 0, stream>>>(z, g1, be1, s2);

    // layer 2: fused bn+if+T-mean
    gemm_splitk<<<dim3(NROWS / BM, DIM / BN, 8), 512, 0, stream>>>(
        s2, W2, part, NROWS, DIM, DIM, DIM / 8, DIM);
    reduce_bias<<<MN / 4 / 256, 256, 0, stream>>>(part, b2, z, 8, MN, DIM);
    bn_stats_if_mean<<<DIM / 64, 256, 0, stream>>>(z, g2, be2, sb);

    // readout: [64,2048] x [1000,2048]^T, KS=8 (grid 1*8*8=64)
    gemm_splitk<<<dim3(1, (NC + BN - 1) / BN, 8), 512, 0, stream>>>(
        sb, Wout, part, BATCH, NC, DIM, DIM / 8, NC);
    reduce_bias<<<(BATCH * NC / 4 + 255) / 256, 256, 0, stream>>>(
        part, bout, out, 8, BATCH * NC, NC);
}

// Round 19
// 381.001 us; speedup vs baseline: 1.6740x; 1.0767x over previous
//
#include <hip/hip_runtime.h>

// ---------------------------------------------------------------------------
// SpikingMLP forward. bf16 MFMA GEMMs, split-precision weights (W_hi+W_lo,
// RNE split, converted during staging). R19 = best-measured combination:
// R10's gemm verbatim (128^2, BK=64, 8 waves, single-buf 2-phase, original
// convert, NO setprio — 188 us) + KS=8 everywhere (R11's best-total tail)
// + KSout=32 (readout GEMM parallelism 64->256 blocks).
// ---------------------------------------------------------------------------

#define T_STEPS 8
#define BATCH 64
#define F0 32768
#define DIM 2048
#define NROWS 512
#define NC 1000

typedef __attribute__((ext_vector_type(8))) short short8;   // 8 bf16
typedef __attribute__((ext_vector_type(4))) float f32x4;    // MFMA acc

__device__ __forceinline__ unsigned short bf16_rne(float f) {
    unsigned int u = __float_as_uint(f);
    u += 0x7FFFu + ((u >> 16) & 1u);
    return (unsigned short)(u >> 16);
}

#define BM 128
#define BN 128
#define BK 64

__device__ __forceinline__ short8 lds_frag(const unsigned short* base, int row, int kb) {
    const int off = row * 128 + (kb ^ ((row & 7) << 4));
    return *(const short8*)((const char*)base + off);
}

__global__ __launch_bounds__(512) void gemm_splitk(
    const unsigned short* __restrict__ A, const float* __restrict__ W,
    float* __restrict__ part, int M, int N, int K, int Kpart, int Wrows)
{
    __shared__ unsigned short As[BM * BK];   // 16 KB
    __shared__ unsigned short Hs[BN * BK];   // 16 KB (W hi)
    __shared__ unsigned short Ls[BN * BK];   // 16 KB (W lo)

    // ---- XCD-chunked bijective remap (grid %8==0 at all call sites) ----
    const int gx = gridDim.x, gy = gridDim.y;
    const int nwg = gx * gy * gridDim.z;
    const int lid = blockIdx.x + gx * (blockIdx.y + gy * blockIdx.z);
    const int cpx = nwg >> 3;
    const int nid = (lid & 7) * cpx + (lid >> 3);
    const int bx  = nid % gx;
    const int by  = (nid / gx) % gy;
    const int kz  = nid / (gx * gy);

    const int tid  = threadIdx.x;
    const int lane = tid & 63;
    const int w    = tid >> 6;          // 0..7
    const int bm   = bx * BM;
    const int bn   = by * BN;
    const int ksteps = Kpart / BK;
    const int wm = (w >> 2) * 64;       // 2 M-halves
    const int wn = (w & 3) * 32;        // 4 N-quarters

    f32x4 acc[4][2] = {};

    for (int kt = 0; kt < ksteps; ++kt) {
        const int k0 = kz * Kpart + kt * BK;

        // ---- A tile: global_load_lds, linear dst + XOR'd src ----
#pragma unroll
        for (int c = 0; c < 2; ++c) {
            const int r    = w * 16 + c * 8 + (lane >> 3);
            const int colb = ((lane & 7) * 16) ^ ((r & 7) << 4);
            const char* src = (const char*)A + ((size_t)(bm + r) * K + k0) * 2 + colb;
            unsigned short* dst = &As[(w * 16 + c * 8) * BK];
            __builtin_amdgcn_global_load_lds(
                (const __attribute__((address_space(1))) void*)src,
                (__attribute__((address_space(3))) void*)dst, 16, 0, 0);
        }

        // ---- W tile: fp32 loads -> hi/lo bf16 split -> swizzled ds_write ----
        float4 wv[4];
#pragma unroll
        for (int i = 0; i < 4; ++i) {
            const int q  = tid + 512 * i;
            const int n  = q >> 4;
            const int c4 = q & 15;
            const int gn = min(bn + n, Wrows - 1);
            wv[i] = *(const float4*)&W[(size_t)gn * K + k0 + c4 * 4];
        }
#pragma unroll
        for (int i = 0; i < 4; ++i) {
            const int q  = tid + 512 * i;
            const int n  = q >> 4;
            const int c4 = q & 15;
            const float vf[4] = {wv[i].x, wv[i].y, wv[i].z, wv[i].w};
            unsigned short h[4], l[4];
#pragma unroll
            for (int e = 0; e < 4; ++e) {
                h[e] = bf16_rne(vf[e]);
                const float hf = __uint_as_float((unsigned int)h[e] << 16);
                l[e] = bf16_rne(vf[e] - hf);
            }
            const int off = n * 128 + ((c4 * 8) ^ ((n & 7) << 4));
            *(ushort4*)((char*)Hs + off) = make_ushort4(h[0], h[1], h[2], h[3]);
            *(ushort4*)((char*)Ls + off) = make_ushort4(l[0], l[1], l[2], l[3]);
        }

        __syncthreads();   // drains vmcnt (A dma) + lgkmcnt (W ds_writes)

        // ---- MFMA: acc += A*Whi + A*Wlo (pure LDS->MFMA) ----
#pragma unroll
        for (int kk = 0; kk < 2; ++kk) {
            const int kb = (kk * 32 + (lane >> 4) * 8) * 2;
            short8 a[4], bh[2], bl[2];
#pragma unroll
            for (int i = 0; i < 4; ++i)
                a[i] = lds_frag(As, wm + i * 16 + (lane & 15), kb);
#pragma unroll
            for (int i = 0; i < 2; ++i) {
                const int r = wn + i * 16 + (lane & 15);
                bh[i] = lds_frag(Hs, r, kb);
                bl[i] = lds_frag(Ls, r, kb);
            }
#pragma unroll
            for (int mi = 0; mi < 4; ++mi)
#pragma unroll
                for (int ni = 0; ni < 2; ++ni) {
                    acc[mi][ni] = __builtin_amdgcn_mfma_f32_16x16x32_bf16(
                        a[mi], bh[ni], acc[mi][ni], 0, 0, 0);
                    acc[mi][ni] = __builtin_amdgcn_mfma_f32_16x16x32_bf16(
                        a[mi], bl[ni], acc[mi][ni], 0, 0, 0);
                }
        }
        __syncthreads();
    }

    // ---- epilogue: partial store (C/D: col=lane&15, row=(lane>>4)*4+e) ----
    const size_t zoff = (size_t)kz * M * N;
#pragma unroll
    for (int mi = 0; mi < 4; ++mi) {
        const int gr0 = bm + wm + mi * 16 + (lane >> 4) * 4;
#pragma unroll
        for (int ni = 0; ni < 2; ++ni) {
            const int gc = bn + wn + ni * 16 + (lane & 15);
            if (gc < N) {
#pragma unroll
                for (int e = 0; e < 4; ++e) {
                    const int gr = gr0 + e;
                    if (gr < M) part[zoff + (size_t)gr * N + gc] = acc[mi][ni][e];
                }
            }
        }
    }
}

// part[KS][.][N] summed + bias -> out (fp32)
__global__ __launch_bounds__(256) void reduce_bias(
    const float* __restrict__ part, const float* __restrict__ bias,
    float* __restrict__ out, int KS, int MN, int N)
{
    const int i4 = blockIdx.x * 256 + threadIdx.x;
    if (i4 * 4 >= MN) return;
    float4 s = make_float4(0.f, 0.f, 0.f, 0.f);
    for (int z = 0; z < KS; ++z) {
        const float4 p = *(const float4*)&part[(size_t)z * MN + i4 * 4];
        s.x += p.x; s.y += p.y; s.z += p.z; s.w += p.w;
    }
    const int col = (i4 * 4) % N;
    const float4 b = *(const float4*)&bias[col];
    s.x += b.x; s.y += b.y; s.z += b.z; s.w += b.w;
    *(float4*)&out[(size_t)i4 * 4] = s;
}

// IF neuron on raw input, vectorized x4
__global__ __launch_bounds__(256) void if0_kernel(
    const float* __restrict__ x, unsigned short* __restrict__ s)
{
    const size_t id4 = ((size_t)blockIdx.x * 256 + threadIdx.x) * 4;
    float v0 = 0.f, v1 = 0.f, v2 = 0.f, v3 = 0.f;
#pragma unroll
    for (int t = 0; t < T_STEPS; ++t) {
        const size_t idx = (size_t)t * (BATCH * (size_t)F0) + id4;
        const float4 xv = *(const float4*)&x[idx];
        ushort4 o;
        v0 += xv.x; if (v0 >= 1.f) { o.x = 0x3F80; v0 = 0.f; } else o.x = 0;
        v1 += xv.y; if (v1 >= 1.f) { o.y = 0x3F80; v1 = 0.f; } else o.y = 0;
        v2 += xv.z; if (v2 >= 1.f) { o.z = 0x3F80; v2 = 0.f; } else o.z = 0;
        v3 += xv.w; if (v3 >= 1.f) { o.w = 0x3F80; v3 = 0.f; } else o.w = 0;
        *(ushort4*)&s[idx] = o;
    }
}

// Fused BN stats + BN apply + IF (stats order unchanged)
__global__ __launch_bounds__(256) void bn_stats_if(
    const float* __restrict__ z, const float* __restrict__ g,
    const float* __restrict__ be, unsigned short* __restrict__ s)
{
    __shared__ float ssum[4][64], ssq[4][64];
    __shared__ float ssc[64], ssh[64];
    const int l = threadIdx.x & 63;
    const int q = threadIdx.x >> 6;
    const int f = blockIdx.x * 64 + l;
    float sum = 0.f, sq = 0.f;
    for (int r = q; r < NROWS; r += 4) {
        const float v = z[(size_t)r * DIM + f];
        sum += v; sq += v * v;
    }
    ssum[q][l] = sum; ssq[q][l] = sq;
    __syncthreads();
    if (threadIdx.x < 64) {
        float ts = 0.f, tq = 0.f;
#pragma unroll
        for (int i = 0; i < 4; ++i) { ts += ssum[i][l]; tq += ssq[i][l]; }
        const float mean = ts * (1.0f / NROWS);
        const float var  = tq * (1.0f / NROWS) - mean * mean;
        const float inv  = rsqrtf(var + 1e-5f);
        const float sc   = g[f] * inv;
        ssc[l] = sc;
        ssh[l] = be[f] - mean * sc;
    }
    __syncthreads();
    const float sc = ssc[l];
    const float sh = ssh[l];
    for (int b = q; b < BATCH; b += 4) {
        const int id = b * DIM + f;
        float v = 0.f;
#pragma unroll
        for (int t = 0; t < T_STEPS; ++t) {
            const size_t idx = (size_t)t * (BATCH * DIM) + id;
            v += z[idx] * sc + sh;
            if (v >= 1.0f) { s[idx] = 0x3F80; v = 0.f; }
            else           { s[idx] = 0; }
        }
    }
}

// Layer-2 variant: emit only the T-mean of spikes (bf16, k/8 exact)
__global__ __launch_bounds__(256) void bn_stats_if_mean(
    const float* __restrict__ z, const float* __restrict__ g,
    const float* __restrict__ be, unsigned short* __restrict__ sbar)
{
    __shared__ float ssum[4][64], ssq[4][64];
    __shared__ float ssc[64], ssh[64];
    const int l = threadIdx.x & 63;
    const int q = threadIdx.x >> 6;
    const int f = blockIdx.x * 64 + l;
    float sum = 0.f, sq = 0.f;
    for (int r = q; r < NROWS; r += 4) {
        const float v = z[(size_t)r * DIM + f];
        sum += v; sq += v * v;
    }
    ssum[q][l] = sum; ssq[q][l] = sq;
    __syncthreads();
    if (threadIdx.x < 64) {
        float ts = 0.f, tq = 0.f;
#pragma unroll
        for (int i = 0; i < 4; ++i) { ts += ssum[i][l]; tq += ssq[i][l]; }
        const float mean = ts * (1.0f / NROWS);
        const float var  = tq * (1.0f / NROWS) - mean * mean;
        const float inv  = rsqrtf(var + 1e-5f);
        const float sc   = g[f] * inv;
        ssc[l] = sc;
        ssh[l] = be[f] - mean * sc;
    }
    __syncthreads();
    const float sc = ssc[l];
    const float sh = ssh[l];
    for (int b = q; b < BATCH; b += 4) {
        const int id = b * DIM + f;
        float v = 0.f;
        int cnt = 0;
#pragma unroll
        for (int t = 0; t < T_STEPS; ++t) {
            const size_t idx = (size_t)t * (BATCH * DIM) + id;
            v += z[idx] * sc + sh;
            if (v >= 1.0f) { cnt++; v = 0.f; }
        }
        sbar[id] = bf16_rne((float)cnt * 0.125f);
    }
}

extern "C" void kernel_launch(void* const* d_in, const int* in_sizes, int n_in,
                              void* d_out, int out_size, void* d_ws, size_t ws_size,
                              hipStream_t stream)
{
    const float* x    = (const float*)d_in[0];
    const float* W0   = (const float*)d_in[1];
    const float* b0   = (const float*)d_in[2];
    const float* g0   = (const float*)d_in[3];
    const float* be0  = (const float*)d_in[4];
    const float* W1   = (const float*)d_in[5];
    const float* b1   = (const float*)d_in[6];
    const float* g1   = (const float*)d_in[7];
    const float* be1  = (const float*)d_in[8];
    const float* W2   = (const float*)d_in[9];
    const float* b2   = (const float*)d_in[10];
    const float* g2   = (const float*)d_in[11];
    const float* be2  = (const float*)d_in[12];
    const float* Wout = (const float*)d_in[13];
    const float* bout = (const float*)d_in[14];
    float* out = (float*)d_out;
    (void)in_sizes; (void)n_in; (void)out_size; (void)ws_size;

    char* ws = (char*)d_ws;
    size_t off = 0;
    auto alloc = [&](size_t nbytes) {
        char* p = ws + off;
        off = (off + nbytes + 255) & ~(size_t)255;
        return p;
    };
    unsigned short* s0 = (unsigned short*)alloc((size_t)NROWS * F0 * 2);  // 33.5 MB
    unsigned short* s1 = (unsigned short*)alloc((size_t)NROWS * DIM * 2);
    unsigned short* s2 = (unsigned short*)alloc((size_t)NROWS * DIM * 2);
    unsigned short* sb = (unsigned short*)alloc((size_t)128 * DIM * 2);   // 128-row pad
    float* z    = (float*)alloc((size_t)NROWS * DIM * 4);
    float* part = (float*)alloc((size_t)32 * (size_t)NROWS * DIM * 4 / 8); // covers KS<=8 MN + KSout=32 small

    const int MN = NROWS * DIM;

    // sn0 (vectorized x4)
    if0_kernel<<<(BATCH * (size_t)F0) / 4 / 256, 256, 0, stream>>>(x, s0);

    // layer 0: K=32768, KS=8  (grid 4*16*8=512; ks=64)
    gemm_splitk<<<dim3(NROWS / BM, DIM / BN, 8), 512, 0, stream>>>(
        s0, W0, part, NROWS, DIM, F0, F0 / 8, DIM);
    reduce_bias<<<MN / 4 / 256, 256, 0, stream>>>(part, b0, z, 8, MN, DIM);
    bn_stats_if<<<DIM / 64, 256, 0, stream>>>(z, g0, be0, s1);

    // layer 1: K=2048, KS=8  (grid 512; ks=4)
    gemm_splitk<<<dim3(NROWS / BM, DIM / BN, 8), 512, 0, stream>>>(
        s1, W1, part, NROWS, DIM, DIM, DIM / 8, DIM);
    reduce_bias<<<MN / 4 / 256, 256, 0, stream>>>(part, b1, z, 8, MN, DIM);
    bn_stats_if<<<DIM / 64, 256, 0, stream>>>(z, g1, be1, s2);

    // layer 2: fused bn+if+T-mean
    gemm_splitk<<<dim3(NROWS / BM, DIM / BN, 8), 512, 0, stream>>>(
        s2, W2, part, NROWS, DIM, DIM, DIM / 8, DIM);
    reduce_bias<<<MN / 4 / 256, 256, 0, stream>>>(part, b2, z, 8, MN, DIM);
    bn_stats_if_mean<<<DIM / 64, 256, 0, stream>>>(z, g2, be2, sb);

    // readout: [64,2048] x [1000,2048]^T, KS=32 (grid 1*8*32=256; ks=1)
    gemm_splitk<<<dim3(1, (NC + BN - 1) / BN, 32), 512, 0, stream>>>(
        sb, Wout, part, BATCH, NC, DIM, DIM / 32, NC);
    reduce_bias<<<(BATCH * NC / 4 + 255) / 256, 256, 0, stream>>>(
        part, bout, out, 32, BATCH * NC, NC);
}